// Round 7
// baseline (209.619 us; speedup 1.0000x reference)
//
#include <hip/hip_runtime.h>
#include <cstdint>
#include <cstddef>

// Problem constants
#define B_   2
#define S_   2048
#define D_   1024
#define H_   16
#define DH_  64
#define NROW (B_ * S_)   // 4096 rows for all projection GEMMs

typedef __bf16  bf16x8 __attribute__((ext_vector_type(8)));
typedef __bf16  bf16x4 __attribute__((ext_vector_type(4)));
typedef float   f32x4  __attribute__((ext_vector_type(4)));

#define MFMA16(a, b, c) __builtin_amdgcn_mfma_f32_16x16x32_bf16((a), (b), (c), 0, 0, 0)

__device__ __forceinline__ void gload_lds16(const void* g, void* l) {
  __builtin_amdgcn_global_load_lds(
      (__attribute__((address_space(1))) void*)(g),
      (__attribute__((address_space(3))) void*)(l), 16, 0, 0);
}

// ---------------------------------------------------------------------------
// W-only cast (X inputs are now consumed fp32 directly by gemm_qkv)
struct CastWArgs { const float* src[4]; __bf16* dst[4]; };

__global__ void cast_w(CastWArgs a) {
  const int which = blockIdx.y;
  const int i = blockIdx.x * blockDim.x + threadIdx.x;
  const float4 v = ((const float4*)a.src[which])[i];
  bf16x4 o;
  o[0] = (__bf16)v.x; o[1] = (__bf16)v.y; o[2] = (__bf16)v.z; o[3] = (__bf16)v.w;
  ((bf16x4*)a.dst[which])[i] = o;
}

// ---------------------------------------------------------------------------
// Fused QKV projection, fp32-A edition. blockIdx.z picks (A,W,bias,C).
// 128x128 tile, BK=32. A staged to LDS as fp32 (16 KB) via global_load_lds
// and converted to bf16 at fragment-read time; W staged bf16 (8 KB).
// XOR-swizzled segment order (applied to the GLOBAL fetch address, since the
// LDS dest of global_load_lds is lane-forced): A-frag ds_reads land 2-way
// (free), B-frag 4-way (was 8-way).
// z==2 (V) writes transposed Vt[b][h][d][s]; z<2 natural [row][col].
struct QKVArgs {
  const float* A[3]; const __bf16* W[3]; const float* bias[3]; __bf16* C[3];
};

__global__ __launch_bounds__(256, 2) void gemm_qkv(QKVArgs args) {
  __shared__ float  Asf[128 * 32];   // 16 KB (fp32 A tile)
  __shared__ __bf16 Bs[128 * 32];    //  8 KB
  const int z = blockIdx.z;
  const float* A = args.A[z];
  const __bf16* W = args.W[z];
  const float* bias = args.bias[z];
  __bf16* C = args.C[z];
  const int tid  = threadIdx.x;
  const int lane = tid & 63, wave = tid >> 6;
  const int lo   = lane & 15, quad = lane >> 4;
  const int wr   = wave & 1,  wc   = wave >> 1;
  const int bn   = blockIdx.x, bm = blockIdx.y;
  const float*  Ag = A + (size_t)bn * 128 * D_;
  const __bf16* Wg = W + (size_t)bm * 128 * D_;
  // A staging: 1024 16B-chunks (4 fp32); chunk c: row=c>>3, phys seg c&7
  // holds global seg (c&7)^(row&7).
  const int ar0 = tid >> 3,          as0 = ((tid & 7) ^ (ar0 & 7)) * 4;
  const int ar1 = (tid + 256) >> 3,  as1 = (((tid + 256) & 7) ^ (ar1 & 7)) * 4;
  const int ar2 = (tid + 512) >> 3,  as2 = (((tid + 512) & 7) ^ (ar2 & 7)) * 4;
  const int ar3 = (tid + 768) >> 3,  as3 = (((tid + 768) & 7) ^ (ar3 & 7)) * 4;
  // B staging: 512 16B-chunks (8 bf16); chunk c: row=c>>2, phys seg c&3
  // holds global seg (c&3)^(row&3).
  const int br0 = tid >> 2,          bs0 = (((tid) & 3) ^ (br0 & 3)) * 8;
  const int br1 = (tid + 256) >> 2,  bs1 = (((tid + 256) & 3) ^ (br1 & 3)) * 8;

  f32x4 acc[4][4] = {};
  for (int k0 = 0; k0 < D_; k0 += 32) {
    __syncthreads();
    gload_lds16(Ag + (size_t)ar0 * D_ + k0 + as0, &Asf[tid * 4]);
    gload_lds16(Ag + (size_t)ar1 * D_ + k0 + as1, &Asf[(tid + 256) * 4]);
    gload_lds16(Ag + (size_t)ar2 * D_ + k0 + as2, &Asf[(tid + 512) * 4]);
    gload_lds16(Ag + (size_t)ar3 * D_ + k0 + as3, &Asf[(tid + 768) * 4]);
    gload_lds16(Wg + (size_t)br0 * D_ + k0 + bs0, &Bs[tid * 8]);
    gload_lds16(Wg + (size_t)br1 * D_ + k0 + bs1, &Bs[(tid + 256) * 8]);
    __syncthreads();
    bf16x8 af[4], bfr[4];
    const int m7 = lo & 7, m3 = lo & 3;
#pragma unroll
    for (int i = 0; i < 4; i++) {
      const int row = wr * 64 + i * 16 + lo;
      // logical fp32 segs 2q (elems 8q..8q+3) and 2q+1 (elems 8q+4..8q+7)
      const f32x4 a0 = *(const f32x4*)&Asf[row * 32 + ((2 * quad) ^ m7) * 4];
      const f32x4 a1 = *(const f32x4*)&Asf[row * 32 + ((2 * quad + 1) ^ m7) * 4];
      bf16x8 v;
#pragma unroll
      for (int j = 0; j < 4; j++) { v[j] = (__bf16)a0[j]; v[4 + j] = (__bf16)a1[j]; }
      af[i] = v;
    }
#pragma unroll
    for (int j = 0; j < 4; j++)
      bfr[j] = *(const bf16x8*)&Bs[(wc * 64 + j * 16 + lo) * 32 + (quad ^ m3) * 8];
#pragma unroll
    for (int i = 0; i < 4; i++)
#pragma unroll
      for (int j = 0; j < 4; j++)
        acc[i][j] = MFMA16(af[i], bfr[j], acc[i][j]);
  }
  if (z == 2) {
#pragma unroll
    for (int i = 0; i < 4; i++) {
      const int row0 = bn * 128 + wr * 64 + i * 16 + quad * 4;
      const int bb = row0 >> 11, s = row0 & (S_ - 1);
#pragma unroll
      for (int j = 0; j < 4; j++) {
        const int col = bm * 128 + wc * 64 + j * 16 + lo;
        const int hh = col >> 6, dd = col & 63;
        const float bv = bias[col];
        bf16x4 o;
#pragma unroll
        for (int r = 0; r < 4; r++) o[r] = (__bf16)(acc[i][j][r] + bv);
        *(bf16x4*)&C[((size_t)(bb * H_ + hh) * DH_ + dd) * S_ + s] = o;
      }
    }
  } else {
#pragma unroll
    for (int i = 0; i < 4; i++) {
      const int row = bn * 128 + wr * 64 + i * 16 + quad * 4;
#pragma unroll
      for (int j = 0; j < 4; j++) {
        const int col = bm * 128 + wc * 64 + j * 16 + lo;
        const float bv = bias[col];
#pragma unroll
        for (int r = 0; r < 4; r++)
          C[(size_t)(row + r) * D_ + col] = (__bf16)(acc[i][j][r] + bv);
      }
    }
  }
}

// ---------------------------------------------------------------------------
// Sliding-window attention v5 (unchanged from R6): streaming softmax without
// max subtraction; q-tile 128; K/V double-buffered; XOR-swizzled staging.
__global__ __launch_bounds__(256, 3) void attn_win5(
    const __bf16* __restrict__ Qp, const __bf16* __restrict__ Kp,
    const __bf16* __restrict__ Vt, __bf16* __restrict__ ctx) {
  __shared__ __bf16 smem[25600];  // 51200 B -> 3 blocks/CU
  const int qt = blockIdx.x, h = blockIdx.y, b = blockIdx.z;
  const int q0 = qt * 128;
  const int tid = threadIdx.x, wave = tid >> 6, lane = tid & 63;
  const int lo = lane & 15, quad = lane >> 4;
  const int tmin = (q0 >= 256) ? 0 : ((256 - q0) >> 6);
  const __bf16* Kg = Kp + (size_t)b * S_ * D_ + h * DH_;
  const __bf16* Vg = Vt + (size_t)(b * H_ + h) * DH_ * S_;
  const size_t qbase = ((size_t)b * S_) * D_ + h * DH_;

  const int c0 = tid, c1 = tid + 256;
  const int rA = c0 >> 3, gA = ((c0 & 7) ^ (rA & 7)) * 8;
  const int rB = c1 >> 3, gB = ((c1 & 7) ^ (rB & 7)) * 8;

  auto stageK = [&](int t) {
    const int k0 = q0 - 256 + t * 64;
    const int kb = (t & 1) * 4096;
    gload_lds16(Kg + (size_t)(k0 + rA) * D_ + gA, &smem[kb + c0 * 8]);
    gload_lds16(Kg + (size_t)(k0 + rB) * D_ + gB, &smem[kb + c1 * 8]);
  };
  auto stageV = [&](int t) {
    const int k0 = q0 - 256 + t * 64;
    const int vb = 8192 + (t & 1) * 4096;
    gload_lds16(Vg + (size_t)rA * S_ + k0 + gA, &smem[vb + c0 * 8]);
    gload_lds16(Vg + (size_t)rB * S_ + k0 + gB, &smem[vb + c1 * 8]);
  };

  bf16x8 qf[2][2];
#pragma unroll
  for (int f = 0; f < 2; f++) {
    const int qr = q0 + wave * 32 + f * 16 + lo;
    qf[f][0] = *(const bf16x8*)&Qp[qbase + (size_t)qr * D_ + quad * 8];
    qf[f][1] = *(const bf16x8*)&Qp[qbase + (size_t)qr * D_ + 32 + quad * 8];
  }

  stageK(tmin); stageV(tmin);
  stageK(tmin + 1); stageV(tmin + 1);
  __syncthreads();

  const int g0 = (quad ^ (lo & 7)) * 8;
  const int g1 = ((quad + 4) ^ (lo & 7)) * 8;

  const int pwb = 16384 + wave * 2304;
  float rs[2][4] = {};
  f32x4 oacc[2][4] = {};

#pragma unroll
  for (int t = 0; t < 6; t++) {
    if (t < tmin) continue;
    const int kb = (t & 1) * 4096, vb = 8192 + (t & 1) * 4096;
    const int kmin = t * 64 - 256;
    const bool active =
        (kmin <= wave * 32 + 31) && (kmin + 63 > wave * 32 - 256);
    if (active) {
      f32x4 sc[2][4];
#pragma unroll
      for (int kt = 0; kt < 4; kt++) {
        const int kr = kt * 16 + lo;
        const bf16x8 kf0 = *(const bf16x8*)&smem[kb + kr * 64 + g0];
        const bf16x8 kf1 = *(const bf16x8*)&smem[kb + kr * 64 + g1];
#pragma unroll
        for (int f = 0; f < 2; f++) {
          f32x4 c = {0.f, 0.f, 0.f, 0.f};
          c = MFMA16(qf[f][0], kf0, c);
          c = MFMA16(qf[f][1], kf1, c);
          sc[f][kt] = c;
        }
      }
#pragma unroll
      for (int f = 0; f < 2; f++)
#pragma unroll
        for (int kt = 0; kt < 4; kt++)
#pragma unroll
          for (int r = 0; r < 4; r++) {
            const int delta =
                kmin + kt * 16 + lo - (wave * 32 + f * 16 + quad * 4 + r);
            const bool keep = (delta <= 0) && (delta > -256);
            const float e = __expf(fmaf(sc[f][kt][r], 0.125f, -8.0f));
            const float p = keep ? e : 0.0f;
            sc[f][kt][r] = p;
            rs[f][r] += p;
          }
#pragma unroll
      for (int f = 0; f < 2; f++)
#pragma unroll
        for (int kt = 0; kt < 4; kt++)
#pragma unroll
          for (int r = 0; r < 4; r++)
            smem[pwb + (f * 16 + quad * 4 + r) * 72 + kt * 16 + lo] =
                (__bf16)sc[f][kt][r];
      bf16x8 pf[2][2];
#pragma unroll
      for (int f = 0; f < 2; f++) {
        pf[f][0] = *(const bf16x8*)&smem[pwb + (f * 16 + lo) * 72 + quad * 8];
        pf[f][1] = *(const bf16x8*)&smem[pwb + (f * 16 + lo) * 72 + 32 + quad * 8];
      }
#pragma unroll
      for (int ds = 0; ds < 4; ds++) {
        const bf16x8 vf0 = *(const bf16x8*)&smem[vb + (ds * 16 + lo) * 64 + g0];
        const bf16x8 vf1 = *(const bf16x8*)&smem[vb + (ds * 16 + lo) * 64 + g1];
#pragma unroll
        for (int f = 0; f < 2; f++) {
          oacc[f][ds] = MFMA16(pf[f][0], vf0, oacc[f][ds]);
          oacc[f][ds] = MFMA16(pf[f][1], vf1, oacc[f][ds]);
        }
      }
    }
    if (t < 5) {
      __syncthreads();
      if (t + 2 <= 5) { stageK(t + 2); stageV(t + 2); }
    }
  }

#pragma unroll
  for (int f = 0; f < 2; f++)
#pragma unroll
    for (int r = 0; r < 4; r++)
#pragma unroll
      for (int off = 1; off < 16; off <<= 1)
        rs[f][r] += __shfl_xor(rs[f][r], off);

#pragma unroll
  for (int f = 0; f < 2; f++)
#pragma unroll
    for (int ds = 0; ds < 4; ds++)
#pragma unroll
      for (int r = 0; r < 4; r++) {
        const int qg = q0 + wave * 32 + f * 16 + quad * 4 + r;
        ctx[((size_t)b * S_ + qg) * D_ + h * DH_ + ds * 16 + lo] =
            (__bf16)(oacc[f][ds][r] / rs[f][r]);
      }
}

// ---------------------------------------------------------------------------
// Output projection: 64x128 tile, fp32 out, XOR-swizzled staging (4-way max).
__global__ __launch_bounds__(256, 2) void gemm_o(
    const __bf16* __restrict__ A, const __bf16* __restrict__ W,
    const float* __restrict__ bias, float* __restrict__ C) {
  __shared__ __bf16 As[64 * 32];    // 4 KB
  __shared__ __bf16 Bs[128 * 32];   // 8 KB
  const int tid = threadIdx.x, lane = tid & 63, wave = tid >> 6;
  const int lo = lane & 15, quad = lane >> 4;
  const int wr = wave & 1, wc = wave >> 1;
  const int bn = blockIdx.x, bm = blockIdx.y;
  const __bf16* Ag = A + (size_t)bn * 64 * D_;
  const __bf16* Wg = W + (size_t)bm * 128 * D_;
  const int ra = tid >> 2,          sa = (((tid) & 3) ^ (ra & 3)) * 8;
  const int rb0 = tid >> 2,         sb0 = (((tid) & 3) ^ (rb0 & 3)) * 8;
  const int rb1 = (tid + 256) >> 2, sb1 = (((tid + 256) & 3) ^ (rb1 & 3)) * 8;
  f32x4 acc[2][4] = {};
  for (int k0 = 0; k0 < D_; k0 += 32) {
    __syncthreads();
    gload_lds16(Ag + (size_t)ra * D_ + k0 + sa, &As[tid * 8]);
    gload_lds16(Wg + (size_t)rb0 * D_ + k0 + sb0, &Bs[tid * 8]);
    gload_lds16(Wg + (size_t)rb1 * D_ + k0 + sb1, &Bs[(tid + 256) * 8]);
    __syncthreads();
    bf16x8 af[2], bfr[4];
    const int m3 = lo & 3;
#pragma unroll
    for (int i = 0; i < 2; i++)
      af[i] = *(const bf16x8*)&As[(wr * 32 + i * 16 + lo) * 32 + (quad ^ m3) * 8];
#pragma unroll
    for (int j = 0; j < 4; j++)
      bfr[j] = *(const bf16x8*)&Bs[(wc * 64 + j * 16 + lo) * 32 + (quad ^ m3) * 8];
#pragma unroll
    for (int i = 0; i < 2; i++)
#pragma unroll
      for (int j = 0; j < 4; j++)
        acc[i][j] = MFMA16(af[i], bfr[j], acc[i][j]);
  }
#pragma unroll
  for (int i = 0; i < 2; i++) {
    const int row = bn * 64 + wr * 32 + i * 16 + quad * 4;
#pragma unroll
    for (int j = 0; j < 4; j++) {
      const int col = bm * 128 + wc * 64 + j * 16 + lo;
      const float bv = bias[col];
#pragma unroll
      for (int r = 0; r < 4; r++)
        C[(size_t)(row + r) * D_ + col] = acc[i][j][r] + bv;
    }
  }
}

// ---------------------------------------------------------------------------
extern "C" void kernel_launch(void* const* d_in, const int* in_sizes, int n_in,
                              void* d_out, int out_size, void* d_ws, size_t ws_size,
                              hipStream_t stream) {
  (void)in_sizes; (void)n_in; (void)out_size; (void)ws_size;
  const float* q_in = (const float*)d_in[0];
  const float* k_in = (const float*)d_in[1];
  const float* v_in = (const float*)d_in[2];
  const float* Wq   = (const float*)d_in[3];
  const float* bq   = (const float*)d_in[4];
  const float* Wk   = (const float*)d_in[5];
  const float* bk   = (const float*)d_in[6];
  const float* Wv   = (const float*)d_in[7];
  const float* bv   = (const float*)d_in[8];
  const float* Wo   = (const float*)d_in[9];
  const float* bo   = (const float*)d_in[10];

  const size_t XN = (size_t)NROW * D_;  // 4M elems
  const size_t WN = (size_t)D_ * D_;    // 1M elems
  char* ws = (char*)d_ws;
  __bf16* wqb = (__bf16*)ws; ws += WN * 2;
  __bf16* wkb = (__bf16*)ws; ws += WN * 2;
  __bf16* wvb = (__bf16*)ws; ws += WN * 2;
  __bf16* wob = (__bf16*)ws; ws += WN * 2;
  __bf16* Qp  = (__bf16*)ws; ws += XN * 2;
  __bf16* Kp  = (__bf16*)ws; ws += XN * 2;
  __bf16* Vtp = (__bf16*)ws; ws += XN * 2;  // [B][H][DH][S]
  __bf16* ctx = (__bf16*)ws; ws += XN * 2;

  CastWArgs cw;
  cw.src[0] = Wq; cw.src[1] = Wk; cw.src[2] = Wv; cw.src[3] = Wo;
  cw.dst[0] = wqb; cw.dst[1] = wkb; cw.dst[2] = wvb; cw.dst[3] = wob;
  cast_w<<<dim3((int)(WN / 4 / 256), 4), 256, 0, stream>>>(cw);

  QKVArgs qa;
  qa.A[0] = q_in; qa.A[1] = k_in; qa.A[2] = v_in;
  qa.W[0] = wqb;  qa.W[1] = wkb;  qa.W[2] = wvb;
  qa.bias[0] = bq; qa.bias[1] = bk; qa.bias[2] = bv;
  qa.C[0] = Qp; qa.C[1] = Kp; qa.C[2] = Vtp;
  gemm_qkv<<<dim3(NROW / 128, D_ / 128, 3), 256, 0, stream>>>(qa);

  attn_win5<<<dim3(S_ / 128, H_, B_), 256, 0, stream>>>(Qp, Kp, Vtp, ctx);

  gemm_o<<<dim3(NROW / 64, D_ / 128), 256, 0, stream>>>(ctx, wob, bo, (float*)d_out);
}

// Round 8
// 192.625 us; speedup vs baseline: 1.0882x; 1.0882x over previous
//
#include <hip/hip_runtime.h>
#include <cstdint>
#include <cstddef>

// Problem constants
#define B_   2
#define S_   2048
#define D_   1024
#define H_   16
#define DH_  64
#define NROW (B_ * S_)   // 4096 rows for all projection GEMMs

typedef __bf16  bf16x8 __attribute__((ext_vector_type(8)));
typedef __bf16  bf16x4 __attribute__((ext_vector_type(4)));
typedef float   f32x4  __attribute__((ext_vector_type(4)));

#define MFMA16(a, b, c) __builtin_amdgcn_mfma_f32_16x16x32_bf16((a), (b), (c), 0, 0, 0)

__device__ __forceinline__ void gload_lds16(const void* g, void* l) {
  __builtin_amdgcn_global_load_lds(
      (__attribute__((address_space(1))) void*)(g),
      (__attribute__((address_space(3))) void*)(l), 16, 0, 0);
}

// ---------------------------------------------------------------------------
// single fused cast: 3 X inputs (4096 blocks each) + 4 W inputs (1024 each)
struct CastArgs { const float* src[7]; __bf16* dst[7]; };

__global__ void cast_all(CastArgs a) {
  int b = blockIdx.x, which, idx;
  if (b < 12288) { which = b >> 12; idx = b & 4095; }
  else { b -= 12288; which = 3 + (b >> 10); idx = b & 1023; }
  const int i = idx * 256 + threadIdx.x;
  const float4 v = ((const float4*)a.src[which])[i];
  bf16x4 o;
  o[0] = (__bf16)v.x; o[1] = (__bf16)v.y; o[2] = (__bf16)v.z; o[3] = (__bf16)v.w;
  ((bf16x4*)a.dst[which])[i] = o;
}

// ---------------------------------------------------------------------------
// Fused QKV projection (R6 structure: bf16 A from cast, 8 KB + 8 KB LDS).
// blockIdx.z picks (A,W,bias,C). 128x128 tile, BK=32.
// z==2 (V) writes transposed Vt[b][h][d][s]; z<2 natural [row][col].
// __launch_bounds__(256,3): measured unified usage is ~60 VGPR + 64 AGPR
// = 124 < 170 cap, so no spill; grid 768 = 256 CU x 3 -> exact residency,
// removes the 33% tail round that 2/CU had. (R7's fp32-A staging reverted:
// it inflated the barrier-drained staging 16->24 KB/iter and regressed.)
struct QKVArgs {
  const __bf16* A[3]; const __bf16* W[3]; const float* bias[3]; __bf16* C[3];
};

__global__ __launch_bounds__(256, 3) void gemm_qkv(QKVArgs args) {
  __shared__ __bf16 As[128 * 32];
  __shared__ __bf16 Bs[128 * 32];
  const int z = blockIdx.z;
  const __bf16* A = args.A[z];
  const __bf16* W = args.W[z];
  const float* bias = args.bias[z];
  __bf16* C = args.C[z];
  const int tid  = threadIdx.x;
  const int lane = tid & 63, wave = tid >> 6;
  const int lo   = lane & 15, quad = lane >> 4;
  const int wr   = wave & 1,  wc   = wave >> 1;
  const int bn   = blockIdx.x, bm = blockIdx.y;
  const __bf16* Ag = A + (size_t)bn * 128 * D_;
  const __bf16* Wg = W + (size_t)bm * 128 * D_;
  const int c0 = tid, c1 = tid + 256;
  const int r0 = c0 >> 2, s0 = (c0 & 3) * 8;
  const int r1 = c1 >> 2, s1 = (c1 & 3) * 8;

  f32x4 acc[4][4] = {};
  for (int k0 = 0; k0 < D_; k0 += 32) {
    __syncthreads();
    gload_lds16(Ag + (size_t)r0 * D_ + k0 + s0, &As[c0 * 8]);
    gload_lds16(Ag + (size_t)r1 * D_ + k0 + s1, &As[c1 * 8]);
    gload_lds16(Wg + (size_t)r0 * D_ + k0 + s0, &Bs[c0 * 8]);
    gload_lds16(Wg + (size_t)r1 * D_ + k0 + s1, &Bs[c1 * 8]);
    __syncthreads();
    bf16x8 af[4], bfr[4];
#pragma unroll
    for (int i = 0; i < 4; i++)
      af[i] = *(const bf16x8*)&As[(wr * 64 + i * 16 + lo) * 32 + quad * 8];
#pragma unroll
    for (int j = 0; j < 4; j++)
      bfr[j] = *(const bf16x8*)&Bs[(wc * 64 + j * 16 + lo) * 32 + quad * 8];
#pragma unroll
    for (int i = 0; i < 4; i++)
#pragma unroll
      for (int j = 0; j < 4; j++)
        acc[i][j] = MFMA16(af[i], bfr[j], acc[i][j]);
  }
  if (z == 2) {
#pragma unroll
    for (int i = 0; i < 4; i++) {
      const int row0 = bn * 128 + wr * 64 + i * 16 + quad * 4;
      const int bb = row0 >> 11, s = row0 & (S_ - 1);
#pragma unroll
      for (int j = 0; j < 4; j++) {
        const int col = bm * 128 + wc * 64 + j * 16 + lo;
        const int hh = col >> 6, dd = col & 63;
        const float bv = bias[col];
        bf16x4 o;
#pragma unroll
        for (int r = 0; r < 4; r++) o[r] = (__bf16)(acc[i][j][r] + bv);
        *(bf16x4*)&C[((size_t)(bb * H_ + hh) * DH_ + dd) * S_ + s] = o;
      }
    }
  } else {
#pragma unroll
    for (int i = 0; i < 4; i++) {
      const int row = bn * 128 + wr * 64 + i * 16 + quad * 4;
#pragma unroll
      for (int j = 0; j < 4; j++) {
        const int col = bm * 128 + wc * 64 + j * 16 + lo;
        const float bv = bias[col];
#pragma unroll
        for (int r = 0; r < 4; r++)
          C[(size_t)(row + r) * D_ + col] = (__bf16)(acc[i][j][r] + bv);
      }
    }
  }
}

// ---------------------------------------------------------------------------
// Sliding-window attention v5 (unchanged from R6): streaming softmax without
// max subtraction (p = exp(s*scale - 8), constant cancels in sum(pv)/sum(p));
// q-tile 128 (4 waves x 32 rows); 6 k-tiles of 64, one fully-masked per wave;
// K/V double-buffered; XOR-swizzled 16B-segment staging.
__global__ __launch_bounds__(256, 3) void attn_win5(
    const __bf16* __restrict__ Qp, const __bf16* __restrict__ Kp,
    const __bf16* __restrict__ Vt, __bf16* __restrict__ ctx) {
  __shared__ __bf16 smem[25600];  // 51200 B -> 3 blocks/CU
  const int qt = blockIdx.x, h = blockIdx.y, b = blockIdx.z;
  const int q0 = qt * 128;
  const int tid = threadIdx.x, wave = tid >> 6, lane = tid & 63;
  const int lo = lane & 15, quad = lane >> 4;
  const int tmin = (q0 >= 256) ? 0 : ((256 - q0) >> 6);
  const __bf16* Kg = Kp + (size_t)b * S_ * D_ + h * DH_;
  const __bf16* Vg = Vt + (size_t)(b * H_ + h) * DH_ * S_;
  const size_t qbase = ((size_t)b * S_) * D_ + h * DH_;

  const int c0 = tid, c1 = tid + 256;
  const int rA = c0 >> 3, gA = ((c0 & 7) ^ (rA & 7)) * 8;
  const int rB = c1 >> 3, gB = ((c1 & 7) ^ (rB & 7)) * 8;

  auto stageK = [&](int t) {
    const int k0 = q0 - 256 + t * 64;
    const int kb = (t & 1) * 4096;
    gload_lds16(Kg + (size_t)(k0 + rA) * D_ + gA, &smem[kb + c0 * 8]);
    gload_lds16(Kg + (size_t)(k0 + rB) * D_ + gB, &smem[kb + c1 * 8]);
  };
  auto stageV = [&](int t) {
    const int k0 = q0 - 256 + t * 64;
    const int vb = 8192 + (t & 1) * 4096;
    gload_lds16(Vg + (size_t)rA * S_ + k0 + gA, &smem[vb + c0 * 8]);
    gload_lds16(Vg + (size_t)rB * S_ + k0 + gB, &smem[vb + c1 * 8]);
  };

  bf16x8 qf[2][2];
#pragma unroll
  for (int f = 0; f < 2; f++) {
    const int qr = q0 + wave * 32 + f * 16 + lo;
    qf[f][0] = *(const bf16x8*)&Qp[qbase + (size_t)qr * D_ + quad * 8];
    qf[f][1] = *(const bf16x8*)&Qp[qbase + (size_t)qr * D_ + 32 + quad * 8];
  }

  stageK(tmin); stageV(tmin);
  stageK(tmin + 1); stageV(tmin + 1);
  __syncthreads();

  const int g0 = (quad ^ (lo & 7)) * 8;
  const int g1 = ((quad + 4) ^ (lo & 7)) * 8;

  const int pwb = 16384 + wave * 2304;
  float rs[2][4] = {};
  f32x4 oacc[2][4] = {};

#pragma unroll
  for (int t = 0; t < 6; t++) {
    if (t < tmin) continue;
    const int kb = (t & 1) * 4096, vb = 8192 + (t & 1) * 4096;
    const int kmin = t * 64 - 256;
    const bool active =
        (kmin <= wave * 32 + 31) && (kmin + 63 > wave * 32 - 256);
    if (active) {
      f32x4 sc[2][4];
#pragma unroll
      for (int kt = 0; kt < 4; kt++) {
        const int kr = kt * 16 + lo;
        const bf16x8 kf0 = *(const bf16x8*)&smem[kb + kr * 64 + g0];
        const bf16x8 kf1 = *(const bf16x8*)&smem[kb + kr * 64 + g1];
#pragma unroll
        for (int f = 0; f < 2; f++) {
          f32x4 c = {0.f, 0.f, 0.f, 0.f};
          c = MFMA16(qf[f][0], kf0, c);
          c = MFMA16(qf[f][1], kf1, c);
          sc[f][kt] = c;
        }
      }
#pragma unroll
      for (int f = 0; f < 2; f++)
#pragma unroll
        for (int kt = 0; kt < 4; kt++)
#pragma unroll
          for (int r = 0; r < 4; r++) {
            const int delta =
                kmin + kt * 16 + lo - (wave * 32 + f * 16 + quad * 4 + r);
            const bool keep = (delta <= 0) && (delta > -256);
            const float e = __expf(fmaf(sc[f][kt][r], 0.125f, -8.0f));
            const float p = keep ? e : 0.0f;
            sc[f][kt][r] = p;
            rs[f][r] += p;
          }
#pragma unroll
      for (int f = 0; f < 2; f++)
#pragma unroll
        for (int kt = 0; kt < 4; kt++)
#pragma unroll
          for (int r = 0; r < 4; r++)
            smem[pwb + (f * 16 + quad * 4 + r) * 72 + kt * 16 + lo] =
                (__bf16)sc[f][kt][r];
      bf16x8 pf[2][2];
#pragma unroll
      for (int f = 0; f < 2; f++) {
        pf[f][0] = *(const bf16x8*)&smem[pwb + (f * 16 + lo) * 72 + quad * 8];
        pf[f][1] = *(const bf16x8*)&smem[pwb + (f * 16 + lo) * 72 + 32 + quad * 8];
      }
#pragma unroll
      for (int ds = 0; ds < 4; ds++) {
        const bf16x8 vf0 = *(const bf16x8*)&smem[vb + (ds * 16 + lo) * 64 + g0];
        const bf16x8 vf1 = *(const bf16x8*)&smem[vb + (ds * 16 + lo) * 64 + g1];
#pragma unroll
        for (int f = 0; f < 2; f++) {
          oacc[f][ds] = MFMA16(pf[f][0], vf0, oacc[f][ds]);
          oacc[f][ds] = MFMA16(pf[f][1], vf1, oacc[f][ds]);
        }
      }
    }
    if (t < 5) {
      __syncthreads();
      if (t + 2 <= 5) { stageK(t + 2); stageV(t + 2); }
    }
  }

#pragma unroll
  for (int f = 0; f < 2; f++)
#pragma unroll
    for (int r = 0; r < 4; r++)
#pragma unroll
      for (int off = 1; off < 16; off <<= 1)
        rs[f][r] += __shfl_xor(rs[f][r], off);

#pragma unroll
  for (int f = 0; f < 2; f++)
#pragma unroll
    for (int ds = 0; ds < 4; ds++)
#pragma unroll
      for (int r = 0; r < 4; r++) {
        const int qg = q0 + wave * 32 + f * 16 + quad * 4 + r;
        ctx[((size_t)b * S_ + qg) * D_ + h * DH_ + ds * 16 + lo] =
            (__bf16)(oacc[f][ds][r] / rs[f][r]);
      }
}

// ---------------------------------------------------------------------------
// Output projection (R6 version): 64x128 tile, 512 blocks -> 2/CU, fp32 out.
__global__ __launch_bounds__(256, 2) void gemm_o(
    const __bf16* __restrict__ A, const __bf16* __restrict__ W,
    const float* __restrict__ bias, float* __restrict__ C) {
  __shared__ __bf16 As[64 * 32];    // 4 KB
  __shared__ __bf16 Bs[128 * 32];   // 8 KB
  const int tid = threadIdx.x, lane = tid & 63, wave = tid >> 6;
  const int lo = lane & 15, quad = lane >> 4;
  const int wr = wave & 1, wc = wave >> 1;
  const int bn = blockIdx.x, bm = blockIdx.y;
  const __bf16* Ag = A + (size_t)bn * 64 * D_;
  const __bf16* Wg = W + (size_t)bm * 128 * D_;
  const int ra = tid >> 2, sa = (tid & 3) * 8;
  const int cb0 = tid, cb1 = tid + 256;
  const int rb0 = cb0 >> 2, sb0 = (cb0 & 3) * 8;
  const int rb1 = cb1 >> 2, sb1 = (cb1 & 3) * 8;
  f32x4 acc[2][4] = {};
  for (int k0 = 0; k0 < D_; k0 += 32) {
    __syncthreads();
    gload_lds16(Ag + (size_t)ra * D_ + k0 + sa, &As[tid * 8]);
    gload_lds16(Wg + (size_t)rb0 * D_ + k0 + sb0, &Bs[cb0 * 8]);
    gload_lds16(Wg + (size_t)rb1 * D_ + k0 + sb1, &Bs[cb1 * 8]);
    __syncthreads();
    bf16x8 af[2], bfr[4];
#pragma unroll
    for (int i = 0; i < 2; i++)
      af[i] = *(const bf16x8*)&As[(wr * 32 + i * 16 + lo) * 32 + quad * 8];
#pragma unroll
    for (int j = 0; j < 4; j++)
      bfr[j] = *(const bf16x8*)&Bs[(wc * 64 + j * 16 + lo) * 32 + quad * 8];
#pragma unroll
    for (int i = 0; i < 2; i++)
#pragma unroll
      for (int j = 0; j < 4; j++)
        acc[i][j] = MFMA16(af[i], bfr[j], acc[i][j]);
  }
#pragma unroll
  for (int i = 0; i < 2; i++) {
    const int row = bn * 64 + wr * 32 + i * 16 + quad * 4;
#pragma unroll
    for (int j = 0; j < 4; j++) {
      const int col = bm * 128 + wc * 64 + j * 16 + lo;
      const float bv = bias[col];
#pragma unroll
      for (int r = 0; r < 4; r++)
        C[(size_t)(row + r) * D_ + col] = acc[i][j][r] + bv;
    }
  }
}

// ---------------------------------------------------------------------------
extern "C" void kernel_launch(void* const* d_in, const int* in_sizes, int n_in,
                              void* d_out, int out_size, void* d_ws, size_t ws_size,
                              hipStream_t stream) {
  (void)in_sizes; (void)n_in; (void)out_size; (void)ws_size;
  const float* q_in = (const float*)d_in[0];
  const float* k_in = (const float*)d_in[1];
  const float* v_in = (const float*)d_in[2];
  const float* Wq   = (const float*)d_in[3];
  const float* bq   = (const float*)d_in[4];
  const float* Wk   = (const float*)d_in[5];
  const float* bk   = (const float*)d_in[6];
  const float* Wv   = (const float*)d_in[7];
  const float* bv   = (const float*)d_in[8];
  const float* Wo   = (const float*)d_in[9];
  const float* bo   = (const float*)d_in[10];

  const size_t XN = (size_t)NROW * D_;  // 4M elems
  const size_t WN = (size_t)D_ * D_;    // 1M elems
  char* ws = (char*)d_ws;               // 64 MB total
  __bf16* xq  = (__bf16*)ws; ws += XN * 2;
  __bf16* xk  = (__bf16*)ws; ws += XN * 2;
  __bf16* xv  = (__bf16*)ws; ws += XN * 2;
  __bf16* wqb = (__bf16*)ws; ws += WN * 2;
  __bf16* wkb = (__bf16*)ws; ws += WN * 2;
  __bf16* wvb = (__bf16*)ws; ws += WN * 2;
  __bf16* wob = (__bf16*)ws; ws += WN * 2;
  __bf16* Qp  = (__bf16*)ws; ws += XN * 2;
  __bf16* Kp  = (__bf16*)ws; ws += XN * 2;
  __bf16* Vtp = (__bf16*)ws; ws += XN * 2;  // [B][H][DH][S]
  __bf16* ctx = (__bf16*)ws; ws += XN * 2;

  CastArgs ca;
  ca.src[0] = q_in; ca.src[1] = k_in; ca.src[2] = v_in;
  ca.src[3] = Wq; ca.src[4] = Wk; ca.src[5] = Wv; ca.src[6] = Wo;
  ca.dst[0] = xq; ca.dst[1] = xk; ca.dst[2] = xv;
  ca.dst[3] = wqb; ca.dst[4] = wkb; ca.dst[5] = wvb; ca.dst[6] = wob;
  cast_all<<<16384, 256, 0, stream>>>(ca);

  QKVArgs qa;
  qa.A[0] = xq;  qa.A[1] = xk;  qa.A[2] = xv;
  qa.W[0] = wqb; qa.W[1] = wkb; qa.W[2] = wvb;
  qa.bias[0] = bq; qa.bias[1] = bk; qa.bias[2] = bv;
  qa.C[0] = Qp; qa.C[1] = Kp; qa.C[2] = Vtp;
  gemm_qkv<<<dim3(NROW / 128, D_ / 128, 3), 256, 0, stream>>>(qa);

  attn_win5<<<dim3(S_ / 128, H_, B_), 256, 0, stream>>>(Qp, Kp, Vtp, ctx);

  gemm_o<<<dim3(NROW / 64, D_ / 128), 256, 0, stream>>>(ctx, wob, bo, (float*)d_out);
}

// Round 9
// 186.368 us; speedup vs baseline: 1.1248x; 1.0336x over previous
//
#include <hip/hip_runtime.h>
#include <cstdint>
#include <cstddef>

// Problem constants
#define B_   2
#define S_   2048
#define D_   1024
#define H_   16
#define DH_  64
#define NROW (B_ * S_)   // 4096 rows for all projection GEMMs

typedef __bf16  bf16x8 __attribute__((ext_vector_type(8)));
typedef __bf16  bf16x4 __attribute__((ext_vector_type(4)));
typedef float   f32x4  __attribute__((ext_vector_type(4)));

#define MFMA16(a, b, c) __builtin_amdgcn_mfma_f32_16x16x32_bf16((a), (b), (c), 0, 0, 0)

__device__ __forceinline__ void gload_lds16(const void* g, void* l) {
  __builtin_amdgcn_global_load_lds(
      (__attribute__((address_space(1))) void*)(g),
      (__attribute__((address_space(3))) void*)(l), 16, 0, 0);
}

// ---------------------------------------------------------------------------
// single fused cast: 3 X inputs (4096 blocks each) + 4 W inputs (1024 each)
struct CastArgs { const float* src[7]; __bf16* dst[7]; };

__global__ void cast_all(CastArgs a) {
  int b = blockIdx.x, which, idx;
  if (b < 12288) { which = b >> 12; idx = b & 4095; }
  else { b -= 12288; which = 3 + (b >> 10); idx = b & 1023; }
  const int i = idx * 256 + threadIdx.x;
  const float4 v = ((const float4*)a.src[which])[i];
  bf16x4 o;
  o[0] = (__bf16)v.x; o[1] = (__bf16)v.y; o[2] = (__bf16)v.z; o[3] = (__bf16)v.w;
  ((bf16x4*)a.dst[which])[i] = o;
}

// ---------------------------------------------------------------------------
// Fused QKV projection, BK=64 edition. blockIdx.z picks (A,W,bias,C).
// 128x128 tile, BK=64: 16 K-iterations (half the barrier drains of BK=32),
// 32 KB LDS. XOR-segment swizzle applied to the GLOBAL fetch address of the
// 16B staging chunks (LDS dest of global_load_lds is lane-forced), so
// fragment ds_read_b128 at row-stride 128 B land 2-way (free) instead of
// 16-way. z==2 (V) writes transposed Vt[b][h][d][s]; z<2 natural.
struct QKVArgs {
  const __bf16* A[3]; const __bf16* W[3]; const float* bias[3]; __bf16* C[3];
};

__global__ __launch_bounds__(256, 3) void gemm_qkv(QKVArgs args) {
  __shared__ __bf16 As[128 * 64];   // 16 KB
  __shared__ __bf16 Bs[128 * 64];   // 16 KB
  const int z = blockIdx.z;
  const __bf16* A = args.A[z];
  const __bf16* W = args.W[z];
  const float* bias = args.bias[z];
  __bf16* C = args.C[z];
  const int tid  = threadIdx.x;
  const int lane = tid & 63, wave = tid >> 6;
  const int lo   = lane & 15, quad = lane >> 4;
  const int wr   = wave & 1,  wc   = wave >> 1;
  const int bn   = blockIdx.x, bm = blockIdx.y;
  const __bf16* Ag = A + (size_t)bn * 128 * D_;
  const __bf16* Wg = W + (size_t)bm * 128 * D_;
  // staging: tile = 128 rows x 8 segs of 16B; chunk c: row=c>>3, phys seg
  // c&7 holds global seg (c&7)^(row&7).
  int srow[4], soff[4];
#pragma unroll
  for (int u = 0; u < 4; u++) {
    const int c = tid + u * 256;
    srow[u] = c >> 3;
    soff[u] = (((c & 7) ^ ((c >> 3) & 7)) * 8);
  }

  f32x4 acc[4][4] = {};
  for (int k0 = 0; k0 < D_; k0 += 64) {
    __syncthreads();
#pragma unroll
    for (int u = 0; u < 4; u++) {
      gload_lds16(Ag + (size_t)srow[u] * D_ + k0 + soff[u], &As[(tid + u * 256) * 8]);
      gload_lds16(Wg + (size_t)srow[u] * D_ + k0 + soff[u], &Bs[(tid + u * 256) * 8]);
    }
    __syncthreads();
#pragma unroll
    for (int h = 0; h < 2; h++) {
      bf16x8 af[4], bfr[4];
#pragma unroll
      for (int i = 0; i < 4; i++) {
        const int r = wr * 64 + i * 16 + lo;
        af[i] = *(const bf16x8*)&As[r * 64 + (((h * 4 + quad) ^ (r & 7)) * 8)];
      }
#pragma unroll
      for (int j = 0; j < 4; j++) {
        const int r = wc * 64 + j * 16 + lo;
        bfr[j] = *(const bf16x8*)&Bs[r * 64 + (((h * 4 + quad) ^ (r & 7)) * 8)];
      }
#pragma unroll
      for (int i = 0; i < 4; i++)
#pragma unroll
        for (int j = 0; j < 4; j++)
          acc[i][j] = MFMA16(af[i], bfr[j], acc[i][j]);
    }
  }
  if (z == 2) {
#pragma unroll
    for (int i = 0; i < 4; i++) {
      const int row0 = bn * 128 + wr * 64 + i * 16 + quad * 4;
      const int bb = row0 >> 11, s = row0 & (S_ - 1);
#pragma unroll
      for (int j = 0; j < 4; j++) {
        const int col = bm * 128 + wc * 64 + j * 16 + lo;
        const int hh = col >> 6, dd = col & 63;
        const float bv = bias[col];
        bf16x4 o;
#pragma unroll
        for (int r = 0; r < 4; r++) o[r] = (__bf16)(acc[i][j][r] + bv);
        *(bf16x4*)&C[((size_t)(bb * H_ + hh) * DH_ + dd) * S_ + s] = o;
      }
    }
  } else {
#pragma unroll
    for (int i = 0; i < 4; i++) {
      const int row = bn * 128 + wr * 64 + i * 16 + quad * 4;
#pragma unroll
      for (int j = 0; j < 4; j++) {
        const int col = bm * 128 + wc * 64 + j * 16 + lo;
        const float bv = bias[col];
#pragma unroll
        for (int r = 0; r < 4; r++)
          C[(size_t)(row + r) * D_ + col] = (__bf16)(acc[i][j][r] + bv);
      }
    }
  }
}

// ---------------------------------------------------------------------------
// Sliding-window attention v5 (unchanged from R6/R8): streaming softmax
// without max subtraction; q-tile 128; K/V double-buffered; XOR-swizzled
// 16B-segment staging.
__global__ __launch_bounds__(256, 3) void attn_win5(
    const __bf16* __restrict__ Qp, const __bf16* __restrict__ Kp,
    const __bf16* __restrict__ Vt, __bf16* __restrict__ ctx) {
  __shared__ __bf16 smem[25600];  // 51200 B -> 3 blocks/CU
  const int qt = blockIdx.x, h = blockIdx.y, b = blockIdx.z;
  const int q0 = qt * 128;
  const int tid = threadIdx.x, wave = tid >> 6, lane = tid & 63;
  const int lo = lane & 15, quad = lane >> 4;
  const int tmin = (q0 >= 256) ? 0 : ((256 - q0) >> 6);
  const __bf16* Kg = Kp + (size_t)b * S_ * D_ + h * DH_;
  const __bf16* Vg = Vt + (size_t)(b * H_ + h) * DH_ * S_;
  const size_t qbase = ((size_t)b * S_) * D_ + h * DH_;

  const int c0 = tid, c1 = tid + 256;
  const int rA = c0 >> 3, gA = ((c0 & 7) ^ (rA & 7)) * 8;
  const int rB = c1 >> 3, gB = ((c1 & 7) ^ (rB & 7)) * 8;

  auto stageK = [&](int t) {
    const int k0 = q0 - 256 + t * 64;
    const int kb = (t & 1) * 4096;
    gload_lds16(Kg + (size_t)(k0 + rA) * D_ + gA, &smem[kb + c0 * 8]);
    gload_lds16(Kg + (size_t)(k0 + rB) * D_ + gB, &smem[kb + c1 * 8]);
  };
  auto stageV = [&](int t) {
    const int k0 = q0 - 256 + t * 64;
    const int vb = 8192 + (t & 1) * 4096;
    gload_lds16(Vg + (size_t)rA * S_ + k0 + gA, &smem[vb + c0 * 8]);
    gload_lds16(Vg + (size_t)rB * S_ + k0 + gB, &smem[vb + c1 * 8]);
  };

  bf16x8 qf[2][2];
#pragma unroll
  for (int f = 0; f < 2; f++) {
    const int qr = q0 + wave * 32 + f * 16 + lo;
    qf[f][0] = *(const bf16x8*)&Qp[qbase + (size_t)qr * D_ + quad * 8];
    qf[f][1] = *(const bf16x8*)&Qp[qbase + (size_t)qr * D_ + 32 + quad * 8];
  }

  stageK(tmin); stageV(tmin);
  stageK(tmin + 1); stageV(tmin + 1);
  __syncthreads();

  const int g0 = (quad ^ (lo & 7)) * 8;
  const int g1 = ((quad + 4) ^ (lo & 7)) * 8;

  const int pwb = 16384 + wave * 2304;
  float rs[2][4] = {};
  f32x4 oacc[2][4] = {};

#pragma unroll
  for (int t = 0; t < 6; t++) {
    if (t < tmin) continue;
    const int kb = (t & 1) * 4096, vb = 8192 + (t & 1) * 4096;
    const int kmin = t * 64 - 256;
    const bool active =
        (kmin <= wave * 32 + 31) && (kmin + 63 > wave * 32 - 256);
    if (active) {
      f32x4 sc[2][4];
#pragma unroll
      for (int kt = 0; kt < 4; kt++) {
        const int kr = kt * 16 + lo;
        const bf16x8 kf0 = *(const bf16x8*)&smem[kb + kr * 64 + g0];
        const bf16x8 kf1 = *(const bf16x8*)&smem[kb + kr * 64 + g1];
#pragma unroll
        for (int f = 0; f < 2; f++) {
          f32x4 c = {0.f, 0.f, 0.f, 0.f};
          c = MFMA16(qf[f][0], kf0, c);
          c = MFMA16(qf[f][1], kf1, c);
          sc[f][kt] = c;
        }
      }
#pragma unroll
      for (int f = 0; f < 2; f++)
#pragma unroll
        for (int kt = 0; kt < 4; kt++)
#pragma unroll
          for (int r = 0; r < 4; r++) {
            const int delta =
                kmin + kt * 16 + lo - (wave * 32 + f * 16 + quad * 4 + r);
            const bool keep = (delta <= 0) && (delta > -256);
            const float e = __expf(fmaf(sc[f][kt][r], 0.125f, -8.0f));
            const float p = keep ? e : 0.0f;
            sc[f][kt][r] = p;
            rs[f][r] += p;
          }
#pragma unroll
      for (int f = 0; f < 2; f++)
#pragma unroll
        for (int kt = 0; kt < 4; kt++)
#pragma unroll
          for (int r = 0; r < 4; r++)
            smem[pwb + (f * 16 + quad * 4 + r) * 72 + kt * 16 + lo] =
                (__bf16)sc[f][kt][r];
      bf16x8 pf[2][2];
#pragma unroll
      for (int f = 0; f < 2; f++) {
        pf[f][0] = *(const bf16x8*)&smem[pwb + (f * 16 + lo) * 72 + quad * 8];
        pf[f][1] = *(const bf16x8*)&smem[pwb + (f * 16 + lo) * 72 + 32 + quad * 8];
      }
#pragma unroll
      for (int ds = 0; ds < 4; ds++) {
        const bf16x8 vf0 = *(const bf16x8*)&smem[vb + (ds * 16 + lo) * 64 + g0];
        const bf16x8 vf1 = *(const bf16x8*)&smem[vb + (ds * 16 + lo) * 64 + g1];
#pragma unroll
        for (int f = 0; f < 2; f++) {
          oacc[f][ds] = MFMA16(pf[f][0], vf0, oacc[f][ds]);
          oacc[f][ds] = MFMA16(pf[f][1], vf1, oacc[f][ds]);
        }
      }
    }
    if (t < 5) {
      __syncthreads();
      if (t + 2 <= 5) { stageK(t + 2); stageV(t + 2); }
    }
  }

#pragma unroll
  for (int f = 0; f < 2; f++)
#pragma unroll
    for (int r = 0; r < 4; r++)
#pragma unroll
      for (int off = 1; off < 16; off <<= 1)
        rs[f][r] += __shfl_xor(rs[f][r], off);

#pragma unroll
  for (int f = 0; f < 2; f++)
#pragma unroll
    for (int ds = 0; ds < 4; ds++)
#pragma unroll
      for (int r = 0; r < 4; r++) {
        const int qg = q0 + wave * 32 + f * 16 + quad * 4 + r;
        ctx[((size_t)b * S_ + qg) * D_ + h * DH_ + ds * 16 + lo] =
            (__bf16)(oacc[f][ds][r] / rs[f][r]);
      }
}

// ---------------------------------------------------------------------------
// Output projection, BK=64 + XOR swizzle: 64x128 tile, 16 K-iters, 24 KB LDS,
// 512 blocks -> 2/CU, fp32 out.
__global__ __launch_bounds__(256, 2) void gemm_o(
    const __bf16* __restrict__ A, const __bf16* __restrict__ W,
    const float* __restrict__ bias, float* __restrict__ C) {
  __shared__ __bf16 As[64 * 64];    //  8 KB
  __shared__ __bf16 Bs[128 * 64];   // 16 KB
  const int tid = threadIdx.x, lane = tid & 63, wave = tid >> 6;
  const int lo = lane & 15, quad = lane >> 4;
  const int wr = wave & 1, wc = wave >> 1;
  const int bn = blockIdx.x, bm = blockIdx.y;
  const __bf16* Ag = A + (size_t)bn * 64 * D_;
  const __bf16* Wg = W + (size_t)bm * 128 * D_;
  int arow[2], aoff[2], brow[4], boff[4];
#pragma unroll
  for (int u = 0; u < 2; u++) {
    const int c = tid + u * 256;
    arow[u] = c >> 3; aoff[u] = ((c & 7) ^ ((c >> 3) & 7)) * 8;
  }
#pragma unroll
  for (int u = 0; u < 4; u++) {
    const int c = tid + u * 256;
    brow[u] = c >> 3; boff[u] = ((c & 7) ^ ((c >> 3) & 7)) * 8;
  }
  f32x4 acc[2][4] = {};
  for (int k0 = 0; k0 < D_; k0 += 64) {
    __syncthreads();
#pragma unroll
    for (int u = 0; u < 2; u++)
      gload_lds16(Ag + (size_t)arow[u] * D_ + k0 + aoff[u], &As[(tid + u * 256) * 8]);
#pragma unroll
    for (int u = 0; u < 4; u++)
      gload_lds16(Wg + (size_t)brow[u] * D_ + k0 + boff[u], &Bs[(tid + u * 256) * 8]);
    __syncthreads();
#pragma unroll
    for (int h = 0; h < 2; h++) {
      bf16x8 af[2], bfr[4];
#pragma unroll
      for (int i = 0; i < 2; i++) {
        const int r = wr * 32 + i * 16 + lo;
        af[i] = *(const bf16x8*)&As[r * 64 + (((h * 4 + quad) ^ (r & 7)) * 8)];
      }
#pragma unroll
      for (int j = 0; j < 4; j++) {
        const int r = wc * 64 + j * 16 + lo;
        bfr[j] = *(const bf16x8*)&Bs[r * 64 + (((h * 4 + quad) ^ (r & 7)) * 8)];
      }
#pragma unroll
      for (int i = 0; i < 2; i++)
#pragma unroll
        for (int j = 0; j < 4; j++)
          acc[i][j] = MFMA16(af[i], bfr[j], acc[i][j]);
    }
  }
#pragma unroll
  for (int i = 0; i < 2; i++) {
    const int row = bn * 64 + wr * 32 + i * 16 + quad * 4;
#pragma unroll
    for (int j = 0; j < 4; j++) {
      const int col = bm * 128 + wc * 64 + j * 16 + lo;
      const float bv = bias[col];
#pragma unroll
      for (int r = 0; r < 4; r++)
        C[(size_t)(row + r) * D_ + col] = acc[i][j][r] + bv;
    }
  }
}

// ---------------------------------------------------------------------------
extern "C" void kernel_launch(void* const* d_in, const int* in_sizes, int n_in,
                              void* d_out, int out_size, void* d_ws, size_t ws_size,
                              hipStream_t stream) {
  (void)in_sizes; (void)n_in; (void)out_size; (void)ws_size;
  const float* q_in = (const float*)d_in[0];
  const float* k_in = (const float*)d_in[1];
  const float* v_in = (const float*)d_in[2];
  const float* Wq   = (const float*)d_in[3];
  const float* bq   = (const float*)d_in[4];
  const float* Wk   = (const float*)d_in[5];
  const float* bk   = (const float*)d_in[6];
  const float* Wv   = (const float*)d_in[7];
  const float* bv   = (const float*)d_in[8];
  const float* Wo   = (const float*)d_in[9];
  const float* bo   = (const float*)d_in[10];

  const size_t XN = (size_t)NROW * D_;  // 4M elems
  const size_t WN = (size_t)D_ * D_;    // 1M elems
  char* ws = (char*)d_ws;               // 64 MB total
  __bf16* xq  = (__bf16*)ws; ws += XN * 2;
  __bf16* xk  = (__bf16*)ws; ws += XN * 2;
  __bf16* xv  = (__bf16*)ws; ws += XN * 2;
  __bf16* wqb = (__bf16*)ws; ws += WN * 2;
  __bf16* wkb = (__bf16*)ws; ws += WN * 2;
  __bf16* wvb = (__bf16*)ws; ws += WN * 2;
  __bf16* wob = (__bf16*)ws; ws += WN * 2;
  __bf16* Qp  = (__bf16*)ws; ws += XN * 2;
  __bf16* Kp  = (__bf16*)ws; ws += XN * 2;
  __bf16* Vtp = (__bf16*)ws; ws += XN * 2;  // [B][H][DH][S]
  __bf16* ctx = (__bf16*)ws; ws += XN * 2;

  CastArgs ca;
  ca.src[0] = q_in; ca.src[1] = k_in; ca.src[2] = v_in;
  ca.src[3] = Wq; ca.src[4] = Wk; ca.src[5] = Wv; ca.src[6] = Wo;
  ca.dst[0] = xq; ca.dst[1] = xk; ca.dst[2] = xv;
  ca.dst[3] = wqb; ca.dst[4] = wkb; ca.dst[5] = wvb; ca.dst[6] = wob;
  cast_all<<<16384, 256, 0, stream>>>(ca);

  QKVArgs qa;
  qa.A[0] = xq;  qa.A[1] = xk;  qa.A[2] = xv;
  qa.W[0] = wqb; qa.W[1] = wkb; qa.W[2] = wvb;
  qa.bias[0] = bq; qa.bias[1] = bk; qa.bias[2] = bv;
  qa.C[0] = Qp; qa.C[1] = Kp; qa.C[2] = Vtp;
  gemm_qkv<<<dim3(NROW / 128, D_ / 128, 3), 256, 0, stream>>>(qa);

  attn_win5<<<dim3(S_ / 128, H_, B_), 256, 0, stream>>>(Qp, Kp, Vtp, ctx);

  gemm_o<<<dim3(NROW / 64, D_ / 128), 256, 0, stream>>>(ctx, wob, bo, (float*)d_out);
}

// Round 11
// 183.425 us; speedup vs baseline: 1.1428x; 1.0160x over previous
//
#include <hip/hip_runtime.h>
#include <cstdint>
#include <cstddef>

// Problem constants
#define B_   2
#define S_   2048
#define D_   1024
#define H_   16
#define DH_  64
#define NROW (B_ * S_)   // 4096 rows for all projection GEMMs

typedef __bf16  bf16x8 __attribute__((ext_vector_type(8)));
typedef __bf16  bf16x4 __attribute__((ext_vector_type(4)));
typedef float   f32x4  __attribute__((ext_vector_type(4)));

#define MFMA16(a, b, c) __builtin_amdgcn_mfma_f32_16x16x32_bf16((a), (b), (c), 0, 0, 0)

__device__ __forceinline__ void gload_lds16(const void* g, void* l) {
  __builtin_amdgcn_global_load_lds(
      (__attribute__((address_space(1))) void*)(g),
      (__attribute__((address_space(3))) void*)(l), 16, 0, 0);
}

// ---------------------------------------------------------------------------
// single fused cast: 3 X inputs (4096 blocks each) + 4 W inputs (1024 each)
struct CastArgs { const float* src[7]; __bf16* dst[7]; };

__global__ void cast_all(CastArgs a) {
  int b = blockIdx.x, which, idx;
  if (b < 12288) { which = b >> 12; idx = b & 4095; }
  else { b -= 12288; which = 3 + (b >> 10); idx = b & 1023; }
  const int i = idx * 256 + threadIdx.x;
  const float4 v = ((const float4*)a.src[which])[i];
  bf16x4 o;
  o[0] = (__bf16)v.x; o[1] = (__bf16)v.y; o[2] = (__bf16)v.z; o[3] = (__bf16)v.w;
  ((bf16x4*)a.dst[which])[i] = o;
}

// ---------------------------------------------------------------------------
// Fused QKV projection, BK=64 + XOR swizzle (unchanged from R9).
struct QKVArgs {
  const __bf16* A[3]; const __bf16* W[3]; const float* bias[3]; __bf16* C[3];
};

__global__ __launch_bounds__(256, 3) void gemm_qkv(QKVArgs args) {
  __shared__ __bf16 As[128 * 64];   // 16 KB
  __shared__ __bf16 Bs[128 * 64];   // 16 KB
  const int z = blockIdx.z;
  const __bf16* A = args.A[z];
  const __bf16* W = args.W[z];
  const float* bias = args.bias[z];
  __bf16* C = args.C[z];
  const int tid  = threadIdx.x;
  const int lane = tid & 63, wave = tid >> 6;
  const int lo   = lane & 15, quad = lane >> 4;
  const int wr   = wave & 1,  wc   = wave >> 1;
  const int bn   = blockIdx.x, bm = blockIdx.y;
  const __bf16* Ag = A + (size_t)bn * 128 * D_;
  const __bf16* Wg = W + (size_t)bm * 128 * D_;
  int srow[4], soff[4];
#pragma unroll
  for (int u = 0; u < 4; u++) {
    const int c = tid + u * 256;
    srow[u] = c >> 3;
    soff[u] = (((c & 7) ^ ((c >> 3) & 7)) * 8);
  }

  f32x4 acc[4][4] = {};
  for (int k0 = 0; k0 < D_; k0 += 64) {
    __syncthreads();
#pragma unroll
    for (int u = 0; u < 4; u++) {
      gload_lds16(Ag + (size_t)srow[u] * D_ + k0 + soff[u], &As[(tid + u * 256) * 8]);
      gload_lds16(Wg + (size_t)srow[u] * D_ + k0 + soff[u], &Bs[(tid + u * 256) * 8]);
    }
    __syncthreads();
#pragma unroll
    for (int h = 0; h < 2; h++) {
      bf16x8 af[4], bfr[4];
#pragma unroll
      for (int i = 0; i < 4; i++) {
        const int r = wr * 64 + i * 16 + lo;
        af[i] = *(const bf16x8*)&As[r * 64 + (((h * 4 + quad) ^ (r & 7)) * 8)];
      }
#pragma unroll
      for (int j = 0; j < 4; j++) {
        const int r = wc * 64 + j * 16 + lo;
        bfr[j] = *(const bf16x8*)&Bs[r * 64 + (((h * 4 + quad) ^ (r & 7)) * 8)];
      }
#pragma unroll
      for (int i = 0; i < 4; i++)
#pragma unroll
        for (int j = 0; j < 4; j++)
          acc[i][j] = MFMA16(af[i], bfr[j], acc[i][j]);
    }
  }
  if (z == 2) {
#pragma unroll
    for (int i = 0; i < 4; i++) {
      const int row0 = bn * 128 + wr * 64 + i * 16 + quad * 4;
      const int bb = row0 >> 11, s = row0 & (S_ - 1);
#pragma unroll
      for (int j = 0; j < 4; j++) {
        const int col = bm * 128 + wc * 64 + j * 16 + lo;
        const int hh = col >> 6, dd = col & 63;
        const float bv = bias[col];
        bf16x4 o;
#pragma unroll
        for (int r = 0; r < 4; r++) o[r] = (__bf16)(acc[i][j][r] + bv);
        *(bf16x4*)&C[((size_t)(bb * H_ + hh) * DH_ + dd) * S_ + s] = o;
      }
    }
  } else {
#pragma unroll
    for (int i = 0; i < 4; i++) {
      const int row = bn * 128 + wr * 64 + i * 16 + quad * 4;
#pragma unroll
      for (int j = 0; j < 4; j++) {
        const int col = bm * 128 + wc * 64 + j * 16 + lo;
        const float bv = bias[col];
#pragma unroll
        for (int r = 0; r < 4; r++)
          C[(size_t)(row + r) * D_ + col] = (__bf16)(acc[i][j][r] + bv);
      }
    }
  }
}

// ---------------------------------------------------------------------------
// Sliding-window attention v7: R10's 4-buffer/2-tiles-per-epoch pipeline
// (3 barriers per block) with the LDS overflow FIXED. R10 bug: Pw at
// 32768 + wave*2304 (stride 72, both f) reached elem 41975 > smem[37376]
// -> OOB LDS writes corrupted neighboring tiles (absmax 0.83). Fix: P is
// f-SEQUENTIAL -- per wave a 1024-elem slab (16 rows, stride 64, XOR seg
// swizzle: write ~2-way, read 2-way = free); write P[f], read pf[f],
// overwrite with f=1 (same-wave DS ordering, no barrier). Total smem =
// 36864 elems = 73728 B -> 2 blocks/CU kept.
__global__ __launch_bounds__(256, 2) void attn_win7(
    const __bf16* __restrict__ Qp, const __bf16* __restrict__ Kp,
    const __bf16* __restrict__ Vt, __bf16* __restrict__ ctx) {
  __shared__ __bf16 smem[36864];  // 73728 B
  const int qt = blockIdx.x, h = blockIdx.y, b = blockIdx.z;
  const int q0 = qt * 128;
  const int tid = threadIdx.x, wave = tid >> 6, lane = tid & 63;
  const int lo = lane & 15, quad = lane >> 4;
  const int tmin = (q0 >= 256) ? 0 : ((256 - q0) >> 6);  // 0, 2, or 4
  const __bf16* Kg = Kp + (size_t)b * S_ * D_ + h * DH_;
  const __bf16* Vg = Vt + (size_t)(b * H_ + h) * DH_ * S_;
  const size_t qbase = ((size_t)b * S_) * D_ + h * DH_;

  const int c0 = tid, c1 = tid + 256;
  const int rA = c0 >> 3, gA = ((c0 & 7) ^ (rA & 7)) * 8;
  const int rB = c1 >> 3, gB = ((c1 & 7) ^ (rB & 7)) * 8;

  auto stageK = [&](int t) {
    const int k0 = q0 - 256 + t * 64;
    const int kb = (t & 3) * 4096;
    gload_lds16(Kg + (size_t)(k0 + rA) * D_ + gA, &smem[kb + c0 * 8]);
    gload_lds16(Kg + (size_t)(k0 + rB) * D_ + gB, &smem[kb + c1 * 8]);
  };
  auto stageV = [&](int t) {
    const int k0 = q0 - 256 + t * 64;
    const int vb = 16384 + (t & 3) * 4096;
    gload_lds16(Vg + (size_t)rA * S_ + k0 + gA, &smem[vb + c0 * 8]);
    gload_lds16(Vg + (size_t)rB * S_ + k0 + gB, &smem[vb + c1 * 8]);
  };
  auto stagePair = [&](int p) {  // tiles 2p, 2p+1
    stageK(2 * p); stageV(2 * p);
    stageK(2 * p + 1); stageV(2 * p + 1);
  };

  bf16x8 qf[2][2];
#pragma unroll
  for (int f = 0; f < 2; f++) {
    const int qr = q0 + wave * 32 + f * 16 + lo;
    qf[f][0] = *(const bf16x8*)&Qp[qbase + (size_t)qr * D_ + quad * 8];
    qf[f][1] = *(const bf16x8*)&Qp[qbase + (size_t)qr * D_ + 32 + quad * 8];
  }

  const int p0 = tmin >> 1;
  stagePair(p0);
  if (p0 + 1 <= 2) stagePair(p0 + 1);
  __syncthreads();

  const int g0 = (quad ^ (lo & 7)) * 8;
  const int g1 = ((quad + 4) ^ (lo & 7)) * 8;

  const int pwb = 32768 + wave * 1024;  // 16 rows x 64, XOR seg swizzle
  float rs[2][4] = {};
  f32x4 oacc[2][4] = {};

#pragma unroll
  for (int p = 0; p < 3; p++) {
    if (p < p0) continue;
#pragma unroll
    for (int u = 0; u < 2; u++) {
      const int t = 2 * p + u;
      const int kb = (t & 3) * 4096, vb = 16384 + (t & 3) * 4096;
      const int kmin = t * 64 - 256;
      const bool active =
          (kmin <= wave * 32 + 31) && (kmin + 63 > wave * 32 - 256);
      if (active) {
        f32x4 sc[2][4];
#pragma unroll
        for (int kt = 0; kt < 4; kt++) {
          const int kr = kt * 16 + lo;
          const bf16x8 kf0 = *(const bf16x8*)&smem[kb + kr * 64 + g0];
          const bf16x8 kf1 = *(const bf16x8*)&smem[kb + kr * 64 + g1];
#pragma unroll
          for (int f = 0; f < 2; f++) {
            f32x4 c = {0.f, 0.f, 0.f, 0.f};
            c = MFMA16(qf[f][0], kf0, c);
            c = MFMA16(qf[f][1], kf1, c);
            sc[f][kt] = c;
          }
        }
#pragma unroll
        for (int f = 0; f < 2; f++)
#pragma unroll
          for (int kt = 0; kt < 4; kt++)
#pragma unroll
            for (int r = 0; r < 4; r++) {
              const int delta =
                  kmin + kt * 16 + lo - (wave * 32 + f * 16 + quad * 4 + r);
              const bool keep = (delta <= 0) && (delta > -256);
              const float e = __expf(fmaf(sc[f][kt][r], 0.125f, -8.0f));
              const float pv = keep ? e : 0.0f;
              sc[f][kt][r] = pv;
              rs[f][r] += pv;
            }
        // P: f-sequential through the per-wave slab (write -> read ->
        // overwrite; same-wave DS ordering makes this safe barrier-free).
        // Element (row, col) lives at row*64 + ((col>>3)^(row&7))*8 + (col&7).
        bf16x8 pf[2][2];
#pragma unroll
        for (int f = 0; f < 2; f++) {
#pragma unroll
          for (int kt = 0; kt < 4; kt++)
#pragma unroll
            for (int r = 0; r < 4; r++) {
              const int row = quad * 4 + r;
              const int col = kt * 16 + lo;
              smem[pwb + row * 64 + (((col >> 3) ^ (row & 7)) * 8) + (col & 7)] =
                  (__bf16)sc[f][kt][r];
            }
          pf[f][0] = *(const bf16x8*)&smem[pwb + lo * 64 + g0];
          pf[f][1] = *(const bf16x8*)&smem[pwb + lo * 64 + g1];
        }
#pragma unroll
        for (int ds = 0; ds < 4; ds++) {
          const bf16x8 vf0 = *(const bf16x8*)&smem[vb + (ds * 16 + lo) * 64 + g0];
          const bf16x8 vf1 = *(const bf16x8*)&smem[vb + (ds * 16 + lo) * 64 + g1];
#pragma unroll
          for (int f = 0; f < 2; f++) {
            oacc[f][ds] = MFMA16(pf[f][0], vf0, oacc[f][ds]);
            oacc[f][ds] = MFMA16(pf[f][1], vf1, oacc[f][ds]);
          }
        }
      }
    }
    if (p < 2) {
      __syncthreads();                   // all waves done with buffers (p pair)
      if (p + 2 <= 2) stagePair(p + 2);  // refill; ~2 tiles of compute cover
    }
  }

#pragma unroll
  for (int f = 0; f < 2; f++)
#pragma unroll
    for (int r = 0; r < 4; r++)
#pragma unroll
      for (int off = 1; off < 16; off <<= 1)
        rs[f][r] += __shfl_xor(rs[f][r], off);

#pragma unroll
  for (int f = 0; f < 2; f++)
#pragma unroll
    for (int ds = 0; ds < 4; ds++)
#pragma unroll
      for (int r = 0; r < 4; r++) {
        const int qg = q0 + wave * 32 + f * 16 + quad * 4 + r;
        ctx[((size_t)b * S_ + qg) * D_ + h * DH_ + ds * 16 + lo] =
            (__bf16)(oacc[f][ds][r] / rs[f][r]);
      }
}

// ---------------------------------------------------------------------------
// Output projection, BK=64 + XOR swizzle (unchanged from R9).
__global__ __launch_bounds__(256, 2) void gemm_o(
    const __bf16* __restrict__ A, const __bf16* __restrict__ W,
    const float* __restrict__ bias, float* __restrict__ C) {
  __shared__ __bf16 As[64 * 64];    //  8 KB
  __shared__ __bf16 Bs[128 * 64];   // 16 KB
  const int tid = threadIdx.x, lane = tid & 63, wave = tid >> 6;
  const int lo = lane & 15, quad = lane >> 4;
  const int wr = wave & 1, wc = wave >> 1;
  const int bn = blockIdx.x, bm = blockIdx.y;
  const __bf16* Ag = A + (size_t)bn * 64 * D_;
  const __bf16* Wg = W + (size_t)bm * 128 * D_;
  int arow[2], aoff[2], brow[4], boff[4];
#pragma unroll
  for (int u = 0; u < 2; u++) {
    const int c = tid + u * 256;
    arow[u] = c >> 3; aoff[u] = ((c & 7) ^ ((c >> 3) & 7)) * 8;
  }
#pragma unroll
  for (int u = 0; u < 4; u++) {
    const int c = tid + u * 256;
    brow[u] = c >> 3; boff[u] = ((c & 7) ^ ((c >> 3) & 7)) * 8;
  }
  f32x4 acc[2][4] = {};
  for (int k0 = 0; k0 < D_; k0 += 64) {
    __syncthreads();
#pragma unroll
    for (int u = 0; u < 2; u++)
      gload_lds16(Ag + (size_t)arow[u] * D_ + k0 + aoff[u], &As[(tid + u * 256) * 8]);
#pragma unroll
    for (int u = 0; u < 4; u++)
      gload_lds16(Wg + (size_t)brow[u] * D_ + k0 + boff[u], &Bs[(tid + u * 256) * 8]);
    __syncthreads();
#pragma unroll
    for (int h = 0; h < 2; h++) {
      bf16x8 af[2], bfr[4];
#pragma unroll
      for (int i = 0; i < 2; i++) {
        const int r = wr * 32 + i * 16 + lo;
        af[i] = *(const bf16x8*)&As[r * 64 + (((h * 4 + quad) ^ (r & 7)) * 8)];
      }
#pragma unroll
      for (int j = 0; j < 4; j++) {
        const int r = wc * 64 + j * 16 + lo;
        bfr[j] = *(const bf16x8*)&Bs[r * 64 + (((h * 4 + quad) ^ (r & 7)) * 8)];
      }
#pragma unroll
      for (int i = 0; i < 2; i++)
#pragma unroll
        for (int j = 0; j < 4; j++)
          acc[i][j] = MFMA16(af[i], bfr[j], acc[i][j]);
    }
  }
#pragma unroll
  for (int i = 0; i < 2; i++) {
    const int row = bn * 64 + wr * 32 + i * 16 + quad * 4;
#pragma unroll
    for (int j = 0; j < 4; j++) {
      const int col = bm * 128 + wc * 64 + j * 16 + lo;
      const float bv = bias[col];
#pragma unroll
      for (int r = 0; r < 4; r++)
        C[(size_t)(row + r) * D_ + col] = acc[i][j][r] + bv;
    }
  }
}

// ---------------------------------------------------------------------------
extern "C" void kernel_launch(void* const* d_in, const int* in_sizes, int n_in,
                              void* d_out, int out_size, void* d_ws, size_t ws_size,
                              hipStream_t stream) {
  (void)in_sizes; (void)n_in; (void)out_size; (void)ws_size;
  const float* q_in = (const float*)d_in[0];
  const float* k_in = (const float*)d_in[1];
  const float* v_in = (const float*)d_in[2];
  const float* Wq   = (const float*)d_in[3];
  const float* bq   = (const float*)d_in[4];
  const float* Wk   = (const float*)d_in[5];
  const float* bk   = (const float*)d_in[6];
  const float* Wv   = (const float*)d_in[7];
  const float* bv   = (const float*)d_in[8];
  const float* Wo   = (const float*)d_in[9];
  const float* bo   = (const float*)d_in[10];

  const size_t XN = (size_t)NROW * D_;  // 4M elems
  const size_t WN = (size_t)D_ * D_;    // 1M elems
  char* ws = (char*)d_ws;               // 64 MB total
  __bf16* xq  = (__bf16*)ws; ws += XN * 2;
  __bf16* xk  = (__bf16*)ws; ws += XN * 2;
  __bf16* xv  = (__bf16*)ws; ws += XN * 2;
  __bf16* wqb = (__bf16*)ws; ws += WN * 2;
  __bf16* wkb = (__bf16*)ws; ws += WN * 2;
  __bf16* wvb = (__bf16*)ws; ws += WN * 2;
  __bf16* wob = (__bf16*)ws; ws += WN * 2;
  __bf16* Qp  = (__bf16*)ws; ws += XN * 2;
  __bf16* Kp  = (__bf16*)ws; ws += XN * 2;
  __bf16* Vtp = (__bf16*)ws; ws += XN * 2;  // [B][H][DH][S]
  __bf16* ctx = (__bf16*)ws; ws += XN * 2;

  CastArgs ca;
  ca.src[0] = q_in; ca.src[1] = k_in; ca.src[2] = v_in;
  ca.src[3] = Wq; ca.src[4] = Wk; ca.src[5] = Wv; ca.src[6] = Wo;
  ca.dst[0] = xq; ca.dst[1] = xk; ca.dst[2] = xv;
  ca.dst[3] = wqb; ca.dst[4] = wkb; ca.dst[5] = wvb; ca.dst[6] = wob;
  cast_all<<<16384, 256, 0, stream>>>(ca);

  QKVArgs qa;
  qa.A[0] = xq;  qa.A[1] = xk;  qa.A[2] = xv;
  qa.W[0] = wqb; qa.W[1] = wkb; qa.W[2] = wvb;
  qa.bias[0] = bq; qa.bias[1] = bk; qa.bias[2] = bv;
  qa.C[0] = Qp; qa.C[1] = Kp; qa.C[2] = Vtp;
  gemm_qkv<<<dim3(NROW / 128, D_ / 128, 3), 256, 0, stream>>>(qa);

  attn_win7<<<dim3(S_ / 128, H_, B_), 256, 0, stream>>>(Qp, Kp, Vtp, ctx);

  gemm_o<<<dim3(NROW / 64, D_ / 128), 256, 0, stream>>>(ctx, wob, bo, (float*)d_out);
}